// Round 2
// baseline (27.296 us; speedup 1.0000x reference)
//
#include <hip/hip_runtime.h>

// x: (512, 2048, 64) f32. Per row of 64 floats we need indices
// 0 (sign), 1 (e10), 11 (e0), 12 (m51), 13 (m50) — all in the row's first 64B.
// Outputs concatenated flat in d_out: result (R,2) f32 then sign (R,1) f32.
// R = 512*2048 = 1,048,576 (divisible by 16).
//
// Wave-cooperative load: 4 consecutive lanes read the 4 contiguous float4
// chunks of one row's first 64B -> each global_load_dwordx4 covers 16 rows
// touching only 16 fully-consumed cache lines (vs 64 partially-used lines
// per load in the 1-thread-per-row version). Values redistributed via __shfl
// within each 4-lane group.

__global__ void spike_extract_coop(const float* __restrict__ x,
                                   float* __restrict__ result,
                                   float* __restrict__ sign_out,
                                   int nrows) {
    const int lane = threadIdx.x & 63;
    const int sub  = lane & 3;          // chunk index within row's first 64B
    const int rl   = lane >> 2;         // row within the wave's 16-row group
    const int waves_per_block = blockDim.x >> 6;
    const int wave_id = blockIdx.x * waves_per_block + (threadIdx.x >> 6);
    const int total_waves = gridDim.x * waves_per_block;
    const int ngroups = nrows >> 4;     // 16 rows per wave-iteration

    for (int g = wave_id; g < ngroups; g += total_waves) {
        const int row = (g << 4) + rl;
        // byte addr = row*256 + sub*16 -> 16B aligned
        const float4 c = *reinterpret_cast<const float4*>(
            x + ((size_t)row << 6) + (sub << 2));

        const int base = lane & ~3;
        // Gather the row's scalars across its 4-lane group:
        const float e0  = __shfl(c.w, base + 2, 64);  // float idx 11 (chunk2.w)
        const float m51 = __shfl(c.x, base + 3, 64);  // idx 12 (chunk3.x)
        const float m50 = __shfl(c.y, base + 3, 64);  // idx 13 (chunk3.y)
        const float s   = __shfl(c.x, base,     64);  // idx 0  (chunk0.x)

        if (sub == 0) {
            const float e10 = c.y;                    // idx 1, own register
            // _mux(sel,a,b) = b + sel*(a-b)
            float b0_high = fmaf(e0, m50 - m51, m51);    // mux(e0, m50, m51)
            float b1_high = fmaf(e0, m51 - 1.0f, 1.0f);  // mux(e0, m51, 1)
            float b0      = fmaf(e10, b0_high - e0, e0); // mux(e10, b0_high, e0)
            float b1      = e10 * b1_high;               // mux(e10, b1_high, 0)
            reinterpret_cast<float2*>(result)[row] = make_float2(b1, b0);
        } else if (sub == 1) {
            sign_out[row] = s;   // spread stores over 2 of the 4 lanes
        }
    }
}

extern "C" void kernel_launch(void* const* d_in, const int* in_sizes, int n_in,
                              void* d_out, int out_size, void* d_ws, size_t ws_size,
                              hipStream_t stream) {
    const float* x = (const float*)d_in[0];
    float* out = (float*)d_out;

    int nrows = in_sizes[0] / 64;          // 1,048,576
    float* result = out;                   // nrows * 2 floats
    float* sign_out = out + (size_t)nrows * 2;

    const int block = 256;                 // 4 waves/block -> 64 rows/block-iter
    const int grid = 2048;                 // grid-stride; 8 groups per wave
    spike_extract_coop<<<grid, block, 0, stream>>>(x, result, sign_out, nrows);
}